// Round 30
// baseline (144.395 us; speedup 1.0000x reference)
//
#include <hip/hip_runtime.h>
#include <stdint.h>

// TopKRouter: T=32768, D=1024, E=64, k=2 (device scalar), C=1280 (from out_size).
//
// Correctness model (VERIFIED PASSING r19-r29): np golden = numpy f32
// transliteration.
// logits = x @ W.T + b, K panels [0,512)[512,1024): single-accumulator
//   ascending-k f32 FMA chain per panel, panels summed left-to-right, + b:
//   z = (c1 + c2) + b. softmax f32: AVX512 FLOAT_exp (Cephes, FMA, rint,
//   scalef); SSE npyv 4-lane pairwise sum + SSE3 hadd horizontal; CR divide;
//   exact max-subtract. top-k & capacity sort: ties -> lower index (stable).
// expert_indices stored as f32 values (-1.0f padding).
//
// r30: X LDS staging flipped to TOKEN-major (XTT[t][k], stride 65, SAME
// 16.9KB buffer reused for epilogue) -> one ds_read_b128 feeds 4 k-steps
// (r26/r29: 1 ds_read_b32 per k-step; LDS unit ~1.4x oversubscribed across
// 4 SIMDs + lgkmcnt mixing with s_load W -> VALUBusy stuck at 42%).
// b128 read banks: lane i -> (i+4kq+{0..3})%32, 2-way lane alias = free.
// Differs from failed r28 exactly where it broke: no extra LT buffer,
// b128 not b64, stride 65 not 33. Chain order bit-exact (x->y->z->w = k asc).

#define THREADS 256
#define TSORT 1024
#define KMAX 16

// ---- numpy AVX512 FLOAT_exp replica: Cephes constants, FMA, rint quadrant ---
__device__ __forceinline__ float np_expf_avx512(float x)
{
    const float log2e = 1.442695040888963f;      // NPY_LOG2Ef
    float t = x * log2e;                          // separate mul (vmulps)
    float q = rintf(t);                           // roundscale nearest-even
    float r = fmaf(q, -0.693359375f, x);          // Cody-Waite hi (fma)
    r = fmaf(q, 2.12194440e-4f, r);               // Cody-Waite lo (fma)
    float y = 1.9875691500E-4f;                   // cephes_exp_p0..p5
    y = fmaf(y, r, 1.3981999507E-3f);
    y = fmaf(y, r, 8.3334519073E-3f);
    y = fmaf(y, r, 4.1665795894E-2f);
    y = fmaf(y, r, 1.6666665459E-1f);
    y = fmaf(y, r, 5.0000001201E-1f);
    float rr = r * r;                             // separate mul
    y = fmaf(y, rr, r);                           // poly*r^2 + r
    y = y + 1.0f;
    return ldexpf(y, (int)q);                     // vscalefps (q integral)
}

// ---------------- Kernel T: transpose W (E x D) -> WT (D x E, k-major) -------
__global__ __launch_bounds__(256)
void transpose_w_kernel(const float* __restrict__ W, float* __restrict__ WT,
                        int D, int E)
{
    const int e = blockIdx.x;
    for (int k = threadIdx.x; k < D; k += 256)
        WT[(size_t)k * E + e] = W[(size_t)e * D + k];
}

// ------- Kernel A: f32 partial logits, one 512-wide K-panel chain per block --
// Grid: (T/64)*2 blocks x 512 thr (8 waves). kh = blockIdx.x & 1 selects the
// K panel; tile = blockIdx.x >> 1 selects 64 tokens. lane = token; wave w =
// experts [8w, 8w+8). Per thread: acc[8] f32 chains (ascending k, serial).
// x staged in LDS TOKEN-major XTT[t][k] stride 65; one ds_read_b128 per
// 4 k-steps. W via wave-uniform scalar loads (readfirstlane -> SGPR).
#define KC 64
#define NTILE 8                       // 512 / KC
__global__ __launch_bounds__(512, 8)
void gemm_partial_kernel(const float* __restrict__ x, const float* __restrict__ WT,
                         float* __restrict__ partial, int T, int D, int E)
{
    const int tid  = threadIdx.x;
    const int lane = tid & 63;
    const int w    = tid >> 6;            // 0..7: expert octet
    const int kh   = blockIdx.x & 1;      // K panel
    const int tok0 = (blockIdx.x >> 1) * 64;
    const int kbeg = kh * 512;
    const int wbase = __builtin_amdgcn_readfirstlane(w * 8);

    __shared__ float XT[64 * 65];         // XTT[t][k] stride 65; reused as LT

    float acc[8];
#pragma unroll
    for (int j = 0; j < 8; ++j) acc[j] = 0.0f;

    const int cc = tid & 15;              // float4 index within a 64-float row
    const int r0 = tid >> 4;              // 0..31 (two x rows: r0, r0+32)

    float4 xr0, xr1;
    auto LOADX = [&](int kc) {
        xr0 = *reinterpret_cast<const float4*>(
            x + (size_t)(tok0 + r0) * D + kc + 4 * cc);
        xr1 = *reinterpret_cast<const float4*>(
            x + (size_t)(tok0 + r0 + 32) * D + kc + 4 * cc);
    };
    auto WRITE_LDS = [&]() {
        // token-major: XTT[t][4cc..4cc+3] = x[tok0+t][kc+4cc..]; float4 store
        *reinterpret_cast<float4*>(&XT[r0 * 65 + 4 * cc]) = xr0;
        *reinterpret_cast<float4*>(&XT[(r0 + 32) * 65 + 4 * cc]) = xr1;
    };

    // prologue: stage x tile 0
    LOADX(kbeg);
    WRITE_LDS();
    __syncthreads();

    for (int tile = 0; tile < NTILE; ++tile) {
        // issue next tile's x loads (latency hides under compute)
        if (tile + 1 < NTILE) LOADX(kbeg + (tile + 1) * KC);

        // wave-uniform W panel base for this tile (SGPR arithmetic)
        const float* wpanel = WT + (size_t)(kbeg + tile * KC) * 64 + wbase;

#pragma unroll 4
        for (int kq = 0; kq < KC / 4; ++kq) {
            float4 xq = *reinterpret_cast<const float4*>(
                &XT[lane * 65 + 4 * kq]);            // b128: 4 k-values
            const float* wp0 = wpanel + (4 * kq + 0) * 64;
            const float* wp1 = wpanel + (4 * kq + 1) * 64;
            const float* wp2 = wpanel + (4 * kq + 2) * 64;
            const float* wp3 = wpanel + (4 * kq + 3) * 64;
#pragma unroll
            for (int j = 0; j < 8; ++j) acc[j] = fmaf(xq.x, wp0[j], acc[j]);
#pragma unroll
            for (int j = 0; j < 8; ++j) acc[j] = fmaf(xq.y, wp1[j], acc[j]);
#pragma unroll
            for (int j = 0; j < 8; ++j) acc[j] = fmaf(xq.z, wp2[j], acc[j]);
#pragma unroll
            for (int j = 0; j < 8; ++j) acc[j] = fmaf(xq.w, wp3[j], acc[j]);
        }

        if (tile + 1 < NTILE) {
            __syncthreads();              // all waves done reading this tile
            WRITE_LDS();                  // loads already landed
            __syncthreads();
        }
    }

    // transpose via LDS (reuse XT as LT[t][e], stride 65), coalesced store
    __syncthreads();
#pragma unroll
    for (int j = 0; j < 8; ++j) XT[lane * 65 + w * 8 + j] = acc[j];
    __syncthreads();
    float* out = partial + (size_t)kh * T * 64;
    for (int it = 0; it < 8; ++it) {
        int i = it * 512 + tid;           // 0..4095
        int t = i >> 6, e = i & 63;
        out[(size_t)(tok0 + t) * 64 + e] = XT[t * 65 + e];
    }
}

// --- Kernel B: combine (p0+p1)+bias, numpy f32 softmax, per-token top-k -----
__global__ __launch_bounds__(THREADS)
void softmax_topk_kernel(const float* __restrict__ part0,
                         const float* __restrict__ part1,
                         const float* __restrict__ bias,
                         float* __restrict__ logits_out,
                         float* __restrict__ probs_out,
                         float* __restrict__ pf, int* __restrict__ eid,
                         const int* __restrict__ kptr, int T, int E)
{
    const int lane = threadIdx.x & 63;
    const int wid = threadIdx.x >> 6;
    int token = blockIdx.x * 4 + wid;
    if (token >= T) token = T - 1;

    int k = *kptr;
    if (k > E) k = E;
    if (k > KMAX) k = KMAX;

    size_t idx = (size_t)token * 64 + lane;
    // z = (c1 + c2) + b  -- exact reference panel-fold order
    float z = (part0[idx] + part1[idx]) + bias[lane];
    logits_out[idx] = z;

    float m = z;
#pragma unroll
    for (int d = 1; d < 64; d <<= 1) m = fmaxf(m, __shfl_xor(m, d));

    float e32 = np_expf_avx512(z - m);

    __shared__ float sh[4][64];
    sh[wid][lane] = e32;
    __syncthreads();

    // numpy FLOAT_pairwise_sum, baseline npyv (SSE, 4 lanes), n=64:
    // R_j[l] = e[4j+l] + e[32+4j+l]; lanewise tree; SSE3 hadd horizontal.
    const float* row = sh[wid];
    float s[4];
#pragma unroll
    for (int l = 0; l < 4; ++l) {
        float R0 = row[ 0 + l] + row[32 + l];
        float R1 = row[ 4 + l] + row[36 + l];
        float R2 = row[ 8 + l] + row[40 + l];
        float R3 = row[12 + l] + row[44 + l];
        float R4 = row[16 + l] + row[48 + l];
        float R5 = row[20 + l] + row[52 + l];
        float R6 = row[24 + l] + row[56 + l];
        float R7 = row[28 + l] + row[60 + l];
        s[l] = ((R0 + R1) + (R2 + R3)) + ((R4 + R5) + (R6 + R7));
    }
    float S = (s[0] + s[1]) + (s[2] + s[3]);   // SSE3 hadd horizontal order

    float p = e32 / S;                    // CR f32 divide
    probs_out[idx] = p;

    // per-token top-k on f32 p, tie -> lower expert id
    float pv = p;
    for (int j = 0; j < k; ++j) {
        float bp = pv;
        int be = lane;
#pragma unroll
        for (int d = 1; d < 64; d <<= 1) {
            float op = __shfl_xor(bp, d);
            int oe = __shfl_xor(be, d);
            if (op > bp || (op == bp && oe < be)) { bp = op; be = oe; }
        }
        if (lane == 0) {
            int slot = token * k + j;
            pf[slot] = bp;
            eid[slot] = be;
        }
        if (lane == be) pv = -1.0f;
    }
}

// ---------------- Kernel C: per-expert gather + bitonic sort ----------------
// Key = (f32 prob bits << 32) | (0xFFFFFFFF - slot); descending u64 sort
// == prob desc, tie -> lower slot. 1024 thr, int4 eid scan.
#define MAXN 4096
__global__ __launch_bounds__(TSORT)
void expert_sort_kernel(const float* __restrict__ pf, const int* __restrict__ eid,
                        const int* __restrict__ kptr,
                        float* __restrict__ out_probs, float* __restrict__ out_idx,
                        int T, int E, int C)
{
    __shared__ unsigned long long keys[MAXN];
    __shared__ int cnt;
    const int e = blockIdx.x;
    const int tid = threadIdx.x;
    if (tid == 0) cnt = 0;
    __syncthreads();

    int k = *kptr;
    if (k > E) k = E;
    if (k > KMAX) k = KMAX;
    const int nslots = T * k;

    // vectorized scan: int4 loads (nslots % 4 == 0 for T mult of 64)
    const int4* eid4 = reinterpret_cast<const int4*>(eid);
    const int nvec = nslots >> 2;
    for (int v = tid; v < nvec; v += TSORT) {
        int4 e4 = eid4[v];
        int sbase = v << 2;
        if (e4.x == e) {
            int pos = atomicAdd(&cnt, 1);
            if (pos < MAXN) keys[pos] =
                ((unsigned long long)__float_as_uint(pf[sbase + 0]) << 32)
              | (unsigned long long)(0xFFFFFFFFu - (unsigned)(sbase + 0));
        }
        if (e4.y == e) {
            int pos = atomicAdd(&cnt, 1);
            if (pos < MAXN) keys[pos] =
                ((unsigned long long)__float_as_uint(pf[sbase + 1]) << 32)
              | (unsigned long long)(0xFFFFFFFFu - (unsigned)(sbase + 1));
        }
        if (e4.z == e) {
            int pos = atomicAdd(&cnt, 1);
            if (pos < MAXN) keys[pos] =
                ((unsigned long long)__float_as_uint(pf[sbase + 2]) << 32)
              | (unsigned long long)(0xFFFFFFFFu - (unsigned)(sbase + 2));
        }
        if (e4.w == e) {
            int pos = atomicAdd(&cnt, 1);
            if (pos < MAXN) keys[pos] =
                ((unsigned long long)__float_as_uint(pf[sbase + 3]) << 32)
              | (unsigned long long)(0xFFFFFFFFu - (unsigned)(sbase + 3));
        }
    }
    __syncthreads();

    int n = cnt;
    if (n > MAXN) n = MAXN;

    int P = 1;
    while (P < n) P <<= 1;
    for (int i = n + tid; i < P; i += TSORT) keys[i] = 0ULL;
    __syncthreads();

    for (int size = 2; size <= P; size <<= 1) {
        for (int stride = size >> 1; stride > 0; stride >>= 1) {
            for (int i = tid; i < P; i += TSORT) {
                int j = i ^ stride;
                if (j > i) {
                    unsigned long long a = keys[i], bkey = keys[j];
                    bool up = ((i & size) == 0);
                    bool doswap = up ? (a < bkey) : (a > bkey);
                    if (doswap) { keys[i] = bkey; keys[j] = a; }
                }
            }
            __syncthreads();
        }
    }

    for (int c = tid; c < C; c += TSORT) {
        float prob, idxv;
        if (c < n) {
            unsigned long long kk = keys[c];
            prob = __uint_as_float((unsigned)(kk >> 32));
            unsigned slot = 0xFFFFFFFFu - (unsigned)(kk & 0xFFFFFFFFull);
            idxv = (float)(slot / (unsigned)k);
        } else {
            prob = 0.0f;
            idxv = -1.0f;
        }
        out_probs[(size_t)e * C + c] = prob;
        out_idx[(size_t)e * C + c] = idxv;
    }
}

extern "C" void kernel_launch(void* const* d_in, const int* in_sizes, int n_in,
                              void* d_out, int out_size, void* d_ws, size_t ws_size,
                              hipStream_t stream)
{
    const float* x   = (const float*)d_in[0];
    const float* W   = (const float*)d_in[1];
    const float* b   = (const float*)d_in[2];
    const int* kptr  = (const int*)d_in[3];

    const int E = in_sizes[2];            // 64
    const int D = in_sizes[1] / E;        // 1024
    const int T = in_sizes[0] / D;        // 32768
    const int C = (out_size - 2 * T * E) / (2 * E);   // 1280

    float* out_logits = (float*)d_out;
    float* out_probs  = out_logits + (size_t)T * E;
    float* out_eprobs = out_probs  + (size_t)T * E;
    float* out_eidx   = out_eprobs + (size_t)E * C;

    // workspace: WT (D*E f32) | pf (T*KMAX f32) | eid (T*KMAX i32) | partial
    float* WT  = (float*)d_ws;
    float* pf  = (float*)((char*)d_ws + (size_t)D * E * sizeof(float));
    int*   eid = (int*)((char*)pf + (size_t)T * KMAX * sizeof(float));
    float* partial = (float*)((char*)eid + (size_t)T * KMAX * sizeof(int));

    transpose_w_kernel<<<E, 256, 0, stream>>>(W, WT, D, E);
    gemm_partial_kernel<<<(T / 64) * 2, 512, 0, stream>>>(
        x, WT, partial, T, D, E);
    softmax_topk_kernel<<<(T + 3) / 4, THREADS, 0, stream>>>(
        partial, partial + (size_t)T * 64, b, out_logits, out_probs,
        pf, eid, kptr, T, E);
    expert_sort_kernel<<<E, TSORT, 0, stream>>>(
        pf, eid, kptr, out_eprobs, out_eidx, T, E, C);
}

// Round 31
// 133.651 us; speedup vs baseline: 1.0804x; 1.0804x over previous
//
#include <hip/hip_runtime.h>
#include <stdint.h>

// TopKRouter: T=32768, D=1024, E=64, k=2 (device scalar), C=1280 (from out_size).
//
// Correctness model (VERIFIED PASSING r19-r30): np golden = numpy f32
// transliteration.
// logits = x @ W.T + b, K panels [0,512)[512,1024): single-accumulator
//   ascending-k f32 FMA chain per panel, panels summed left-to-right, + b:
//   z = (c1 + c2) + b. softmax f32: AVX512 FLOAT_exp (Cephes, FMA, rint,
//   scalef); SSE npyv 4-lane pairwise sum + SSE3 hadd horizontal; CR divide;
//   exact max-subtract. top-k & capacity sort: ties -> lower index (stable).
// expert_indices stored as f32 values (-1.0f padding).
//
// r31: FINAL restore of r26 config (session optimum, measured 133.8us twice:
// gemm 82us, VALUBusy 42%, occ 80%). Five structured GEMM alternatives all
// regressed: r24 interleaved-stage 114, r27 acc16 107, r28 paired-b64 92,
// r30 token-major-b128 87-96. The bit-exact serial-chain constraint forbids
// MFMA; the ~80us gemm is this structure's empirical floor at HIP level.

#define THREADS 256
#define TSORT 1024
#define KMAX 16

// ---- numpy AVX512 FLOAT_exp replica: Cephes constants, FMA, rint quadrant ---
__device__ __forceinline__ float np_expf_avx512(float x)
{
    const float log2e = 1.442695040888963f;      // NPY_LOG2Ef
    float t = x * log2e;                          // separate mul (vmulps)
    float q = rintf(t);                           // roundscale nearest-even
    float r = fmaf(q, -0.693359375f, x);          // Cody-Waite hi (fma)
    r = fmaf(q, 2.12194440e-4f, r);               // Cody-Waite lo (fma)
    float y = 1.9875691500E-4f;                   // cephes_exp_p0..p5
    y = fmaf(y, r, 1.3981999507E-3f);
    y = fmaf(y, r, 8.3334519073E-3f);
    y = fmaf(y, r, 4.1665795894E-2f);
    y = fmaf(y, r, 1.6666665459E-1f);
    y = fmaf(y, r, 5.0000001201E-1f);
    float rr = r * r;                             // separate mul
    y = fmaf(y, rr, r);                           // poly*r^2 + r
    y = y + 1.0f;
    return ldexpf(y, (int)q);                     // vscalefps (q integral)
}

// ---------------- Kernel T: transpose W (E x D) -> WT (D x E, k-major) -------
__global__ __launch_bounds__(256)
void transpose_w_kernel(const float* __restrict__ W, float* __restrict__ WT,
                        int D, int E)
{
    const int e = blockIdx.x;
    for (int k = threadIdx.x; k < D; k += 256)
        WT[(size_t)k * E + e] = W[(size_t)e * D + k];
}

// ------- Kernel A: f32 partial logits, one 512-wide K-panel chain per block --
// Grid: (T/64)*2 blocks x 512 thr (8 waves). kh = blockIdx.x & 1 selects the
// K panel; tile = blockIdx.x >> 1 selects 64 tokens. lane = token; wave w =
// experts [8w, 8w+8). Per thread: acc[8] f32 chains (ascending k, serial).
// x staged in LDS (transposed, stride 65, conflict-free, async-stage split);
// W read via wave-uniform SCALAR loads (readfirstlane offset -> SGPR).
#define KC 64
#define NTILE 8                       // 512 / KC
__global__ __launch_bounds__(512, 8)
void gemm_partial_kernel(const float* __restrict__ x, const float* __restrict__ WT,
                         float* __restrict__ partial, int T, int D, int E)
{
    const int tid  = threadIdx.x;
    const int lane = tid & 63;
    const int w    = tid >> 6;            // 0..7: expert octet
    const int kh   = blockIdx.x & 1;      // K panel
    const int tok0 = (blockIdx.x >> 1) * 64;
    const int kbeg = kh * 512;
    // wave-uniform expert-octet offset, hoisted to SGPR
    const int wbase = __builtin_amdgcn_readfirstlane(w * 8);

    __shared__ float XT[64 * 65];         // XT[k][t] stride 65; reused as LT

    float acc[8];
#pragma unroll
    for (int j = 0; j < 8; ++j) acc[j] = 0.0f;

    const int cc = tid & 15;              // float4 index within a 64-float row
    const int r0 = tid >> 4;              // 0..31 (two x rows: r0, r0+32)

    float4 xr0, xr1;
    auto LOADX = [&](int kc) {
        xr0 = *reinterpret_cast<const float4*>(
            x + (size_t)(tok0 + r0) * D + kc + 4 * cc);
        xr1 = *reinterpret_cast<const float4*>(
            x + (size_t)(tok0 + r0 + 32) * D + kc + 4 * cc);
    };
    auto WRITE_LDS = [&]() {
        XT[(4 * cc + 0) * 65 + r0] = xr0.x;
        XT[(4 * cc + 1) * 65 + r0] = xr0.y;
        XT[(4 * cc + 2) * 65 + r0] = xr0.z;
        XT[(4 * cc + 3) * 65 + r0] = xr0.w;
        XT[(4 * cc + 0) * 65 + r0 + 32] = xr1.x;
        XT[(4 * cc + 1) * 65 + r0 + 32] = xr1.y;
        XT[(4 * cc + 2) * 65 + r0 + 32] = xr1.z;
        XT[(4 * cc + 3) * 65 + r0 + 32] = xr1.w;
    };

    // prologue: stage x tile 0
    LOADX(kbeg);
    WRITE_LDS();
    __syncthreads();

    for (int tile = 0; tile < NTILE; ++tile) {
        // issue next tile's x loads (latency hides under compute)
        if (tile + 1 < NTILE) LOADX(kbeg + (tile + 1) * KC);

        // wave-uniform W panel base for this tile (SGPR arithmetic)
        const float* wpanel = WT + (size_t)(kbeg + tile * KC) * 64 + wbase;

#pragma unroll 8
        for (int k = 0; k < KC; ++k) {
            float xv = XT[k * 65 + lane];
            const float* wp = wpanel + k * 64;   // uniform -> scalar loads
            float w0 = wp[0], w1 = wp[1], w2 = wp[2], w3 = wp[3];
            float w4 = wp[4], w5 = wp[5], w6 = wp[6], w7 = wp[7];
            acc[0] = fmaf(xv, w0, acc[0]);
            acc[1] = fmaf(xv, w1, acc[1]);
            acc[2] = fmaf(xv, w2, acc[2]);
            acc[3] = fmaf(xv, w3, acc[3]);
            acc[4] = fmaf(xv, w4, acc[4]);
            acc[5] = fmaf(xv, w5, acc[5]);
            acc[6] = fmaf(xv, w6, acc[6]);
            acc[7] = fmaf(xv, w7, acc[7]);
        }

        if (tile + 1 < NTILE) {
            __syncthreads();              // all waves done reading this tile
            WRITE_LDS();                  // loads already landed
            __syncthreads();
        }
    }

    // transpose via LDS (reuse XT as LT[t][e], stride 65), coalesced store
    __syncthreads();
#pragma unroll
    for (int j = 0; j < 8; ++j) XT[lane * 65 + w * 8 + j] = acc[j];
    __syncthreads();
    float* out = partial + (size_t)kh * T * 64;
    for (int it = 0; it < 8; ++it) {
        int i = it * 512 + tid;           // 0..4095
        int t = i >> 6, e = i & 63;
        out[(size_t)(tok0 + t) * 64 + e] = XT[t * 65 + e];
    }
}

// --- Kernel B: combine (p0+p1)+bias, numpy f32 softmax, per-token top-k -----
__global__ __launch_bounds__(THREADS)
void softmax_topk_kernel(const float* __restrict__ part0,
                         const float* __restrict__ part1,
                         const float* __restrict__ bias,
                         float* __restrict__ logits_out,
                         float* __restrict__ probs_out,
                         float* __restrict__ pf, int* __restrict__ eid,
                         const int* __restrict__ kptr, int T, int E)
{
    const int lane = threadIdx.x & 63;
    const int wid = threadIdx.x >> 6;
    int token = blockIdx.x * 4 + wid;
    if (token >= T) token = T - 1;

    int k = *kptr;
    if (k > E) k = E;
    if (k > KMAX) k = KMAX;

    size_t idx = (size_t)token * 64 + lane;
    // z = (c1 + c2) + b  -- exact reference panel-fold order
    float z = (part0[idx] + part1[idx]) + bias[lane];
    logits_out[idx] = z;

    float m = z;
#pragma unroll
    for (int d = 1; d < 64; d <<= 1) m = fmaxf(m, __shfl_xor(m, d));

    float e32 = np_expf_avx512(z - m);

    __shared__ float sh[4][64];
    sh[wid][lane] = e32;
    __syncthreads();

    // numpy FLOAT_pairwise_sum, baseline npyv (SSE, 4 lanes), n=64:
    // R_j[l] = e[4j+l] + e[32+4j+l]; lanewise tree; SSE3 hadd horizontal.
    const float* row = sh[wid];
    float s[4];
#pragma unroll
    for (int l = 0; l < 4; ++l) {
        float R0 = row[ 0 + l] + row[32 + l];
        float R1 = row[ 4 + l] + row[36 + l];
        float R2 = row[ 8 + l] + row[40 + l];
        float R3 = row[12 + l] + row[44 + l];
        float R4 = row[16 + l] + row[48 + l];
        float R5 = row[20 + l] + row[52 + l];
        float R6 = row[24 + l] + row[56 + l];
        float R7 = row[28 + l] + row[60 + l];
        s[l] = ((R0 + R1) + (R2 + R3)) + ((R4 + R5) + (R6 + R7));
    }
    float S = (s[0] + s[1]) + (s[2] + s[3]);   // SSE3 hadd horizontal order

    float p = e32 / S;                    // CR f32 divide
    probs_out[idx] = p;

    // per-token top-k on f32 p, tie -> lower expert id
    float pv = p;
    for (int j = 0; j < k; ++j) {
        float bp = pv;
        int be = lane;
#pragma unroll
        for (int d = 1; d < 64; d <<= 1) {
            float op = __shfl_xor(bp, d);
            int oe = __shfl_xor(be, d);
            if (op > bp || (op == bp && oe < be)) { bp = op; be = oe; }
        }
        if (lane == 0) {
            int slot = token * k + j;
            pf[slot] = bp;
            eid[slot] = be;
        }
        if (lane == be) pv = -1.0f;
    }
}

// ---------------- Kernel C: per-expert gather + bitonic sort ----------------
// Key = (f32 prob bits << 32) | (0xFFFFFFFF - slot); descending u64 sort
// == prob desc, tie -> lower slot. 1024 thr, int4 eid scan.
#define MAXN 4096
__global__ __launch_bounds__(TSORT)
void expert_sort_kernel(const float* __restrict__ pf, const int* __restrict__ eid,
                        const int* __restrict__ kptr,
                        float* __restrict__ out_probs, float* __restrict__ out_idx,
                        int T, int E, int C)
{
    __shared__ unsigned long long keys[MAXN];
    __shared__ int cnt;
    const int e = blockIdx.x;
    const int tid = threadIdx.x;
    if (tid == 0) cnt = 0;
    __syncthreads();

    int k = *kptr;
    if (k > E) k = E;
    if (k > KMAX) k = KMAX;
    const int nslots = T * k;

    // vectorized scan: int4 loads (nslots % 4 == 0 for T mult of 64)
    const int4* eid4 = reinterpret_cast<const int4*>(eid);
    const int nvec = nslots >> 2;
    for (int v = tid; v < nvec; v += TSORT) {
        int4 e4 = eid4[v];
        int sbase = v << 2;
        if (e4.x == e) {
            int pos = atomicAdd(&cnt, 1);
            if (pos < MAXN) keys[pos] =
                ((unsigned long long)__float_as_uint(pf[sbase + 0]) << 32)
              | (unsigned long long)(0xFFFFFFFFu - (unsigned)(sbase + 0));
        }
        if (e4.y == e) {
            int pos = atomicAdd(&cnt, 1);
            if (pos < MAXN) keys[pos] =
                ((unsigned long long)__float_as_uint(pf[sbase + 1]) << 32)
              | (unsigned long long)(0xFFFFFFFFu - (unsigned)(sbase + 1));
        }
        if (e4.z == e) {
            int pos = atomicAdd(&cnt, 1);
            if (pos < MAXN) keys[pos] =
                ((unsigned long long)__float_as_uint(pf[sbase + 2]) << 32)
              | (unsigned long long)(0xFFFFFFFFu - (unsigned)(sbase + 2));
        }
        if (e4.w == e) {
            int pos = atomicAdd(&cnt, 1);
            if (pos < MAXN) keys[pos] =
                ((unsigned long long)__float_as_uint(pf[sbase + 3]) << 32)
              | (unsigned long long)(0xFFFFFFFFu - (unsigned)(sbase + 3));
        }
    }
    __syncthreads();

    int n = cnt;
    if (n > MAXN) n = MAXN;

    int P = 1;
    while (P < n) P <<= 1;
    for (int i = n + tid; i < P; i += TSORT) keys[i] = 0ULL;
    __syncthreads();

    for (int size = 2; size <= P; size <<= 1) {
        for (int stride = size >> 1; stride > 0; stride >>= 1) {
            for (int i = tid; i < P; i += TSORT) {
                int j = i ^ stride;
                if (j > i) {
                    unsigned long long a = keys[i], bkey = keys[j];
                    bool up = ((i & size) == 0);
                    bool doswap = up ? (a < bkey) : (a > bkey);
                    if (doswap) { keys[i] = bkey; keys[j] = a; }
                }
            }
            __syncthreads();
        }
    }

    for (int c = tid; c < C; c += TSORT) {
        float prob, idxv;
        if (c < n) {
            unsigned long long kk = keys[c];
            prob = __uint_as_float((unsigned)(kk >> 32));
            unsigned slot = 0xFFFFFFFFu - (unsigned)(kk & 0xFFFFFFFFull);
            idxv = (float)(slot / (unsigned)k);
        } else {
            prob = 0.0f;
            idxv = -1.0f;
        }
        out_probs[(size_t)e * C + c] = prob;
        out_idx[(size_t)e * C + c] = idxv;
    }
}

extern "C" void kernel_launch(void* const* d_in, const int* in_sizes, int n_in,
                              void* d_out, int out_size, void* d_ws, size_t ws_size,
                              hipStream_t stream)
{
    const float* x   = (const float*)d_in[0];
    const float* W   = (const float*)d_in[1];
    const float* b   = (const float*)d_in[2];
    const int* kptr  = (const int*)d_in[3];

    const int E = in_sizes[2];            // 64
    const int D = in_sizes[1] / E;        // 1024
    const int T = in_sizes[0] / D;        // 32768
    const int C = (out_size - 2 * T * E) / (2 * E);   // 1280

    float* out_logits = (float*)d_out;
    float* out_probs  = out_logits + (size_t)T * E;
    float* out_eprobs = out_probs  + (size_t)T * E;
    float* out_eidx   = out_eprobs + (size_t)E * C;

    // workspace: WT (D*E f32) | pf (T*KMAX f32) | eid (T*KMAX i32) | partial
    float* WT  = (float*)d_ws;
    float* pf  = (float*)((char*)d_ws + (size_t)D * E * sizeof(float));
    int*   eid = (int*)((char*)pf + (size_t)T * KMAX * sizeof(float));
    float* partial = (float*)((char*)eid + (size_t)T * KMAX * sizeof(int));

    transpose_w_kernel<<<E, 256, 0, stream>>>(W, WT, D, E);
    gemm_partial_kernel<<<(T / 64) * 2, 512, 0, stream>>>(
        x, WT, partial, T, D, E);
    softmax_topk_kernel<<<(T + 3) / 4, THREADS, 0, stream>>>(
        partial, partial + (size_t)T * 64, b, out_logits, out_probs,
        pf, eid, kptr, T, E);
    expert_sort_kernel<<<E, TSORT, 0, stream>>>(
        pf, eid, kptr, out_eprobs, out_eidx, T, E, C);
}